// Round 5
// baseline (1232.507 us; speedup 1.0000x reference)
//
#include <hip/hip_runtime.h>
#include <hip/hip_fp16.h>

#define SEQ   512
#define BATCH 64
#define EMB   256
#define HID   512

// recurrence W_hh split: 192 f16-pairs (384 cols) in VGPRs, 64 pairs (128 cols) in LDS
#define CR 192
#define CL 64
#define WLROW 68  // pairs per LDS row (64 used + 4 pad): 272B = odd multiple of 16B

typedef _Float16 half2v __attribute__((ext_vector_type(2)));
typedef _Float16 half8v __attribute__((ext_vector_type(8)));  // 16B ds_read_b128

__device__ __forceinline__ float dot2acc(half2v a, half2v b, float c) {
#if defined(__has_builtin)
#if __has_builtin(__builtin_amdgcn_fdot2)
  return __builtin_amdgcn_fdot2(a, b, c, false);
#else
  return fmaf((float)a[0], (float)b[0], fmaf((float)a[1], (float)b[1], c));
#endif
#else
  return fmaf((float)a[0], (float)b[0], fmaf((float)a[1], (float)b[1], c));
#endif
}

__device__ __forceinline__ float fast_tanh(float x) {
  x = fminf(fmaxf(x, -15.f), 15.f);
  float e = __expf(2.f * x);
  return (e - 1.f) / (e + 1.f);
}

// X[t][b][j] = sum_e emb[text[t][b]][e] * W_ih[j][e] + b_ih[j] + b_hh[j], stored f16
// grid = SEQ blocks, 512 threads (thread = output unit j). emb rows are
// wave-uniform per b -> scalar (s_load) path; W_ih row chunk lives in 32 VGPRs.
__global__ __launch_bounds__(512, 2) void proj_kernel(
    const int* __restrict__ text, const float* __restrict__ emb,
    const float* __restrict__ Wih, const float* __restrict__ bih,
    const float* __restrict__ bhh, __half* __restrict__ X) {
  const int t = blockIdx.x;
  const int j = threadIdx.x;

  float acc[BATCH];
#pragma unroll
  for (int b = 0; b < BATCH; ++b) acc[b] = 0.f;

  for (int ec = 0; ec < EMB / 32; ++ec) {
    float w[32];
    const float4* wp = reinterpret_cast<const float4*>(Wih + (size_t)j * EMB + ec * 32);
#pragma unroll
    for (int q = 0; q < 8; ++q) {
      float4 v = wp[q];
      w[4 * q + 0] = v.x; w[4 * q + 1] = v.y; w[4 * q + 2] = v.z; w[4 * q + 3] = v.w;
    }
#pragma unroll
    for (int b = 0; b < BATCH; ++b) {
      int tok = __builtin_amdgcn_readfirstlane(text[t * BATCH + b]);  // uniform
      const float* ar = emb + (size_t)tok * EMB + ec * 32;
#pragma unroll
      for (int e = 0; e < 32; ++e) acc[b] = fmaf(w[e], ar[e], acc[b]);
    }
  }

  const float bias = bih[j] + bhh[j];
#pragma unroll
  for (int b = 0; b < BATCH; ++b)
    X[((size_t)t * BATCH + b) * HID + j] = __float2half(acc[b] + bias);
}

// One block per batch element. Thread j owns h[j]. W_hh row j: cols [0,384)
// as 192 packed-f16 pairs in VGPRs, cols [384,512) in LDS laid out [j][pair]
// with 272B row stride (16B-aligned b128 reads, minimal bank pattern).
// h kept as f16 pairs in LDS (double-buffered -> 1 barrier/step), broadcast
// b128 reads. f32 accumulation via v_dot2_f32_f16.
__global__ __launch_bounds__(512, 2) void rnn_kernel(
    const __half* __restrict__ X, const float* __restrict__ Whh,
    const float* __restrict__ Wfc, const float* __restrict__ bfc,
    float* __restrict__ out) {
  __shared__ __align__(16) half2v Wl[HID * WLROW];   // 136 KB
  __shared__ __align__(16) half2v h2[2][HID / 2];    // 2 KB
  __shared__ float red[16];

  const int j = threadIdx.x;
  const int b = blockIdx.x;

  const float* wr = Whh + (size_t)j * HID;

  // register-resident part: pairs [0, CR)
  half2v w[CR];
#pragma unroll
  for (int c = 0; c < CR; ++c) {
    float2 v = reinterpret_cast<const float2*>(wr)[c];
    half2v h; h[0] = (_Float16)v.x; h[1] = (_Float16)v.y;
    w[c] = h;
  }
  // LDS-resident part: pairs [CR, CR+CL) -> Wl row j
#pragma unroll
  for (int c = 0; c < CL; ++c) {
    float2 v = reinterpret_cast<const float2*>(wr)[CR + c];
    half2v h; h[0] = (_Float16)v.x; h[1] = (_Float16)v.y;
    Wl[j * WLROW + c] = h;
  }
  if (j < HID / 2) {
    half2v z; z[0] = (_Float16)0.f; z[1] = (_Float16)0.f;
    h2[0][j] = z;
  }
  __syncthreads();

  const __half* Xp = X + (size_t)b * HID + j;  // stride per t = BATCH*HID
  float xv = __half2float(Xp[0]);
  float h = 0.f;
  int cur = 0;

  for (int t = 0; t < SEQ; ++t) {
    const int tn = (t < SEQ - 1) ? t + 1 : t;
    float xnext = __half2float(Xp[(size_t)tn * BATCH * HID]);

    const half8v* hp = reinterpret_cast<const half8v*>(&h2[cur][0]);
    const half8v* wl = reinterpret_cast<const half8v*>(&Wl[j * WLROW]);

    float a0 = 0.f, a1 = 0.f, a2 = 0.f, a3 = 0.f;
#pragma unroll
    for (int q = 0; q < CR / 4; ++q) {
      half8v hv = hp[q];  // uniform addr -> broadcast ds_read_b128
      half2v h0 = {hv[0], hv[1]}, h1 = {hv[2], hv[3]};
      half2v h2p = {hv[4], hv[5]}, h3 = {hv[6], hv[7]};
      a0 = dot2acc(w[4 * q + 0], h0, a0);
      a1 = dot2acc(w[4 * q + 1], h1, a1);
      a2 = dot2acc(w[4 * q + 2], h2p, a2);
      a3 = dot2acc(w[4 * q + 3], h3, a3);
    }
#pragma unroll
    for (int q = 0; q < CL / 4; ++q) {
      half8v hv = hp[CR / 4 + q];  // broadcast
      half8v wv = wl[q];           // per-lane b128, conflict-minimal stride
      half2v h0 = {hv[0], hv[1]}, h1 = {hv[2], hv[3]};
      half2v h2p = {hv[4], hv[5]}, h3 = {hv[6], hv[7]};
      half2v w0 = {wv[0], wv[1]}, w1 = {wv[2], wv[3]};
      half2v w2 = {wv[4], wv[5]}, w3 = {wv[6], wv[7]};
      a0 = dot2acc(w0, h0, a0);
      a1 = dot2acc(w1, h1, a1);
      a2 = dot2acc(w2, h2p, a2);
      a3 = dot2acc(w3, h3, a3);
    }

    float acc = ((a0 + a1) + (a2 + a3)) + xv;
    h = fast_tanh(acc);
    xv = xnext;

    // write new h to the other buffer; one barrier publishes it and protects
    // the buffer being read (reads hit cur, writes hit cur^1).
    reinterpret_cast<__half*>(&h2[cur ^ 1][0])[j] = __float2half(h);
    __syncthreads();
    cur ^= 1;
  }

  // final FC: out[b][o] = sum_j W_fc[o][j]*h[j] + b_fc[o]
  float c0 = Wfc[j] * h;
  float c1 = Wfc[HID + j] * h;
#pragma unroll
  for (int o = 32; o > 0; o >>= 1) {
    c0 += __shfl_down(c0, o, 64);
    c1 += __shfl_down(c1, o, 64);
  }
  const int wave = j >> 6;
  if ((j & 63) == 0) { red[wave] = c0; red[8 + wave] = c1; }
  __syncthreads();
  if (j == 0) {
    float s0 = 0.f, s1 = 0.f;
#pragma unroll
    for (int i = 0; i < 8; ++i) { s0 += red[i]; s1 += red[8 + i]; }
    out[b * 2 + 0] = s0 + bfc[0];
    out[b * 2 + 1] = s1 + bfc[1];
  }
}

extern "C" void kernel_launch(void* const* d_in, const int* in_sizes, int n_in,
                              void* d_out, int out_size, void* d_ws, size_t ws_size,
                              hipStream_t stream) {
  const int*   text = (const int*)d_in[0];
  const float* emb  = (const float*)d_in[1];
  const float* Wih  = (const float*)d_in[2];
  const float* Whh  = (const float*)d_in[3];
  const float* bih  = (const float*)d_in[4];
  const float* bhh  = (const float*)d_in[5];
  const float* Wfc  = (const float*)d_in[6];
  const float* bfc  = (const float*)d_in[7];
  float* outp = (float*)d_out;

  __half* X = (__half*)d_ws;  // SEQ*BATCH*HID f16 = 32 MiB

  proj_kernel<<<SEQ, 512, 0, stream>>>(text, emb, Wih, bih, bhh, X);
  rnn_kernel<<<BATCH, 512, 0, stream>>>(X, Whh, Wfc, bfc, outp);
}

// Round 6
// 996.640 us; speedup vs baseline: 1.2367x; 1.2367x over previous
//
#include <hip/hip_runtime.h>
#include <hip/hip_fp16.h>

#define SEQ   512
#define BATCH 64
#define EMB   256
#define HID   512

// recurrence W_hh split: 192 f16-pairs (384 cols) in VGPRs, 64 pairs (128 cols) in LDS
#define CR 192
#define CL 64
#define WLROW 68  // pairs per LDS row (64 used + 4 pad): 272B stride

typedef _Float16 half2v __attribute__((ext_vector_type(2)));
typedef _Float16 half8v __attribute__((ext_vector_type(8)));  // 16B ds_read_b128

__device__ __forceinline__ float dot2acc(half2v a, half2v b, float c) {
#if defined(__has_builtin)
#if __has_builtin(__builtin_amdgcn_fdot2)
  return __builtin_amdgcn_fdot2(a, b, c, false);
#else
  return fmaf((float)a[0], (float)b[0], fmaf((float)a[1], (float)b[1], c));
#endif
#else
  return fmaf((float)a[0], (float)b[0], fmaf((float)a[1], (float)b[1], c));
#endif
}

__device__ __forceinline__ float fast_tanh(float x) {
  x = fminf(fmaxf(x, -15.f), 15.f);
  float e = __expf(2.f * x);
  return (e - 1.f) / (e + 1.f);
}

// X[t][b][j] = dot(emb[text[t][b]], W_ih[j]) + b_ih[j] + b_hh[j], stored f16.
// grid = SEQ blocks, 512 threads (thread = output unit j).
// emb rows staged once per block into LDS as f16 (coalesced float4 global
// loads), then consumed as b128 broadcasts; inner product via v_dot2_f32_f16.
__global__ __launch_bounds__(512) void proj_kernel(
    const int* __restrict__ text, const float* __restrict__ emb,
    const float* __restrict__ Wih, const float* __restrict__ bih,
    const float* __restrict__ bhh, __half* __restrict__ X) {
  __shared__ __align__(16) __half se[BATCH][EMB];  // 32 KB
  __shared__ int stok[BATCH];

  const int t = blockIdx.x;
  const int j = threadIdx.x;

  if (j < BATCH) stok[j] = text[t * BATCH + j];
  __syncthreads();

  // stage emb rows: thread j covers row r = j>>3, elems (j&7)*32 .. +32
  {
    const int r = j >> 3;
    const int c0 = (j & 7) * 32;
    const float4* src = reinterpret_cast<const float4*>(emb + (size_t)stok[r] * EMB + c0);
    half2v* rowp = reinterpret_cast<half2v*>(&se[r][0]);
#pragma unroll
    for (int q = 0; q < 8; ++q) {
      float4 v = src[q];
      half2v p0; p0[0] = (_Float16)v.x; p0[1] = (_Float16)v.y;
      half2v p1; p1[0] = (_Float16)v.z; p1[1] = (_Float16)v.w;
      rowp[c0 / 2 + 2 * q + 0] = p0;
      rowp[c0 / 2 + 2 * q + 1] = p1;
    }
  }
  __syncthreads();

  float acc[BATCH];
#pragma unroll
  for (int b = 0; b < BATCH; ++b) acc[b] = 0.f;

  for (int ec = 0; ec < EMB / 32; ++ec) {
    // 32 W_ih coefficients for row j as 16 f16 pairs
    half2v wh[16];
    const float4* wp = reinterpret_cast<const float4*>(Wih + (size_t)j * EMB + ec * 32);
#pragma unroll
    for (int q = 0; q < 8; ++q) {
      float4 v = wp[q];
      wh[2 * q + 0][0] = (_Float16)v.x; wh[2 * q + 0][1] = (_Float16)v.y;
      wh[2 * q + 1][0] = (_Float16)v.z; wh[2 * q + 1][1] = (_Float16)v.w;
    }
#pragma unroll
    for (int b = 0; b < BATCH; ++b) {
      const half8v* ep = reinterpret_cast<const half8v*>(&se[b][ec * 32]);  // broadcast
      float a = acc[b];
#pragma unroll
      for (int r = 0; r < 4; ++r) {
        half8v ev = ep[r];
        half2v e0 = {ev[0], ev[1]}, e1 = {ev[2], ev[3]};
        half2v e2 = {ev[4], ev[5]}, e3 = {ev[6], ev[7]};
        a = dot2acc(wh[4 * r + 0], e0, a);
        a = dot2acc(wh[4 * r + 1], e1, a);
        a = dot2acc(wh[4 * r + 2], e2, a);
        a = dot2acc(wh[4 * r + 3], e3, a);
      }
      acc[b] = a;
    }
  }

  const float bias = bih[j] + bhh[j];
#pragma unroll
  for (int b = 0; b < BATCH; ++b)
    X[((size_t)t * BATCH + b) * HID + j] = __float2half(acc[b] + bias);
}

// One block per batch element. Thread j owns h[j]. W_hh row j: cols [0,384)
// as 192 packed-f16 pairs in VGPRs, cols [384,512) in LDS laid out [j][pair].
// h kept as f16 pairs in LDS (double-buffered -> 1 barrier/step), broadcast
// b128 reads. f32 accumulation via v_dot2_f32_f16.
// waves_per_eu(2,2): LDS (138.5 KB) forces 1 block/CU = 2 waves/SIMD; telling
// the register allocator min=max=2 makes the full 256-VGPR budget usable so
// w[CR] stays in registers (round-5 build capped at 128 VGPRs and spilled
// w to scratch: WRITE_SIZE 21 MB on a 512-byte-output kernel).
__global__ __launch_bounds__(512)
__attribute__((amdgpu_waves_per_eu(2, 2)))
void rnn_kernel(
    const __half* __restrict__ X, const float* __restrict__ Whh,
    const float* __restrict__ Wfc, const float* __restrict__ bfc,
    float* __restrict__ out) {
  __shared__ __align__(16) half2v Wl[HID * WLROW];   // 136 KB
  __shared__ __align__(16) half2v h2[2][HID / 2];    // 2 KB
  __shared__ float red[16];

  const int j = threadIdx.x;
  const int b = blockIdx.x;

  const float* wr = Whh + (size_t)j * HID;

  // register-resident part: pairs [0, CR)
  half2v w[CR];
#pragma unroll
  for (int c = 0; c < CR; ++c) {
    float2 v = reinterpret_cast<const float2*>(wr)[c];
    half2v h; h[0] = (_Float16)v.x; h[1] = (_Float16)v.y;
    w[c] = h;
  }
  // LDS-resident part: pairs [CR, CR+CL) -> Wl row j
#pragma unroll
  for (int c = 0; c < CL; ++c) {
    float2 v = reinterpret_cast<const float2*>(wr)[CR + c];
    half2v h; h[0] = (_Float16)v.x; h[1] = (_Float16)v.y;
    Wl[j * WLROW + c] = h;
  }
  if (j < HID / 2) {
    half2v z; z[0] = (_Float16)0.f; z[1] = (_Float16)0.f;
    h2[0][j] = z;
  }
  __syncthreads();

  const __half* Xp = X + (size_t)b * HID + j;  // stride per t = BATCH*HID
  float xv = __half2float(Xp[0]);
  float h = 0.f;
  int cur = 0;

  for (int t = 0; t < SEQ; ++t) {
    const int tn = (t < SEQ - 1) ? t + 1 : t;
    float xnext = __half2float(Xp[(size_t)tn * BATCH * HID]);

    const half8v* hp = reinterpret_cast<const half8v*>(&h2[cur][0]);
    const half8v* wl = reinterpret_cast<const half8v*>(&Wl[j * WLROW]);

    float a0 = 0.f, a1 = 0.f, a2 = 0.f, a3 = 0.f;
#pragma unroll
    for (int q = 0; q < CR / 4; ++q) {
      half8v hv = hp[q];  // uniform addr -> broadcast ds_read_b128
      half2v h0 = {hv[0], hv[1]}, h1 = {hv[2], hv[3]};
      half2v h2p = {hv[4], hv[5]}, h3 = {hv[6], hv[7]};
      a0 = dot2acc(w[4 * q + 0], h0, a0);
      a1 = dot2acc(w[4 * q + 1], h1, a1);
      a2 = dot2acc(w[4 * q + 2], h2p, a2);
      a3 = dot2acc(w[4 * q + 3], h3, a3);
    }
#pragma unroll
    for (int q = 0; q < CL / 4; ++q) {
      half8v hv = hp[CR / 4 + q];  // broadcast
      half8v wv = wl[q];           // per-lane b128
      half2v h0 = {hv[0], hv[1]}, h1 = {hv[2], hv[3]};
      half2v h2p = {hv[4], hv[5]}, h3 = {hv[6], hv[7]};
      half2v w0 = {wv[0], wv[1]}, w1 = {wv[2], wv[3]};
      half2v w2 = {wv[4], wv[5]}, w3 = {wv[6], wv[7]};
      a0 = dot2acc(w0, h0, a0);
      a1 = dot2acc(w1, h1, a1);
      a2 = dot2acc(w2, h2p, a2);
      a3 = dot2acc(w3, h3, a3);
    }

    float acc = ((a0 + a1) + (a2 + a3)) + xv;
    h = fast_tanh(acc);
    xv = xnext;

    // write new h to the other buffer; one barrier publishes it and protects
    // the buffer being read (reads hit cur, writes hit cur^1).
    reinterpret_cast<__half*>(&h2[cur ^ 1][0])[j] = __float2half(h);
    __syncthreads();
    cur ^= 1;
  }

  // final FC: out[b][o] = sum_j W_fc[o][j]*h[j] + b_fc[o]
  float c0 = Wfc[j] * h;
  float c1 = Wfc[HID + j] * h;
#pragma unroll
  for (int o = 32; o > 0; o >>= 1) {
    c0 += __shfl_down(c0, o, 64);
    c1 += __shfl_down(c1, o, 64);
  }
  const int wave = j >> 6;
  if ((j & 63) == 0) { red[wave] = c0; red[8 + wave] = c1; }
  __syncthreads();
  if (j == 0) {
    float s0 = 0.f, s1 = 0.f;
#pragma unroll
    for (int i = 0; i < 8; ++i) { s0 += red[i]; s1 += red[8 + i]; }
    out[b * 2 + 0] = s0 + bfc[0];
    out[b * 2 + 1] = s1 + bfc[1];
  }
}

extern "C" void kernel_launch(void* const* d_in, const int* in_sizes, int n_in,
                              void* d_out, int out_size, void* d_ws, size_t ws_size,
                              hipStream_t stream) {
  const int*   text = (const int*)d_in[0];
  const float* emb  = (const float*)d_in[1];
  const float* Wih  = (const float*)d_in[2];
  const float* Whh  = (const float*)d_in[3];
  const float* bih  = (const float*)d_in[4];
  const float* bhh  = (const float*)d_in[5];
  const float* Wfc  = (const float*)d_in[6];
  const float* bfc  = (const float*)d_in[7];
  float* outp = (float*)d_out;

  __half* X = (__half*)d_ws;  // SEQ*BATCH*HID f16 = 32 MiB

  proj_kernel<<<SEQ, 512, 0, stream>>>(text, emb, Wih, bih, bhh, X);
  rnn_kernel<<<BATCH, 512, 0, stream>>>(X, Whh, Wfc, bfc, outp);
}